// Round 6
// baseline (218.400 us; speedup 1.0000x reference)
//
#include <hip/hip_runtime.h>

// Bilateral denoiser, 1080x1920x11 fp32 -> 1080x1920x3 fp32.
// d^2 <= 36 taps (113). Two y-adjacent pixels per thread packed into
// v_pk_*_f32 lanes (f2).
//
// R6: instruction diet. Occupancy lever is dead (R2/R4/R5: resident waves
// pin at ~12/CU regardless of static cap; VALUBusy ~80%). Fitted issue
// model: 116 cy/tap = 52 VOP + 4 trans x 16 cy (trans = 4 lanes/cy,
// serializes with VALU issue -- measured busy == sum, no overlap).
// Cuts:
//  (a) w_normal back to 7 packed squarings (R1 path): 2 logs + pk_fma
//      (36 cy) -> 7 pk_mul + merge mul (32 cy), trans/tap 4 -> 2.
//  (b) depth-slope hoist: r2 = max(invdC*rdz, RCLAMP) depends only on
//      (d^2, pixel); 19 distinct d^2 over all taps. Precompute r2d[19]
//      (f2) once; tap fma reads the component via compile-time slot
//      (register operand selection, zero ops): -8 cy/tap.
// Per-tap 116 -> 104 cy. Geometry: best-measured R2 tile 32x16, 256 thr,
// slim LDS (float4 A + float2/float B = 28 B/px, 34496 B/block).
// All r2d indices are compile-time (loops fully unrolled) -- no scratch.

namespace {
constexpr int IMG_H = 1080;
constexpr int IMG_W = 1920;
constexpr int CHN   = 11;
constexpr int TLX   = 32;
constexpr int TLY   = 16;
constexpr int HALO  = 6;
constexpr int RX    = TLX + 2 * HALO;   // 44
constexpr int RY    = TLY + 2 * HALO;   // 28
constexpr int PY    = 2;
constexpr int R2MAX = 36;

constexpr double CD = -1.4426950408889634;   // -log2(e)

// distinct d^2 values <= 36 (a^2+b^2, a,b in 0..6)
constexpr int NS = 19;
constexpr int D2V[NS] = {0,1,2,4,5,8,9,10,13,16,17,18,20,25,26,29,32,34,36};

constexpr float icOf(int d2) {
    if (d2 == 0) return -1e30f;          // center: forces r2 -> RCLAMP; lw=0
    double s = (double)d2, x = s;
    for (int it = 0; it < 60; ++it) x = 0.5 * (x + s / x);
    return (float)(CD / x);              // -log2e / dist
}

struct ICTab {
    float v[NS];
    constexpr ICTab() : v{} { for (int k = 0; k < NS; ++k) v[k] = icOf(D2V[k]); }
};
constexpr ICTab IC{};

constexpr int slotOf(int dy, int dx) {
    const int d2 = dy * dy + dx * dx;
    for (int k = 0; k < NS; ++k) if (D2V[k] == d2) return k;
    return 1;                            // inactive half (d2>36): any finite slot
}
constexpr float lwOf(int dy, int dx) {
    const int d2 = dy * dy + dx * dx;
    if (d2 == 0) return 0.f;
    if (d2 <= R2MAX) return (float)(0.5 * CD * d2);  // -log2e/2 * d^2
    return -1e30f;                       // pruned/out-of-window: w -> 0
}
}

typedef float f2 __attribute__((ext_vector_type(2)));

__global__ __launch_bounds__(256, 4)
void bilateral_denoise_kernel(const float* __restrict__ in, float* __restrict__ out) {
    __shared__ float4 ldsA[RY * RX];    // {col0, col1, col2, z}   19712 B
    __shared__ float2 ldsB01[RY * RX];  // {nrm0, nrm1}             9856 B
    __shared__ float  ldsB2[RY * RX];   // nrm2                     4928 B
                                        // total 34496 B -> 4 blocks/CU

    const int lx  = threadIdx.x;
    const int ty  = threadIdx.y;
    const int bx0 = blockIdx.x * TLX;
    const int by0 = blockIdx.y * TLY;
    const int tid = ty * 32 + lx;

    // ---- stage tile + halo (OOB -> zeros; nrm=0 => dot=0 => c^128=0 => w=0) ----
    for (int r = tid; r < RY * RX; r += 256) {
        const int ry = r / RX;
        const int rx = r - ry * RX;
        const int gy = by0 - HALO + ry;
        const int gx = bx0 - HALO + rx;
        float4 A = make_float4(0.f, 0.f, 0.f, 0.f);
        float2 Bxy = make_float2(0.f, 0.f);
        float  Bz = 0.f;
        if ((unsigned)gy < (unsigned)IMG_H && (unsigned)gx < (unsigned)IMG_W) {
            const float* p = in + (gy * IMG_W + gx) * CHN;
            A.x = p[0]; A.y = p[1]; A.z = p[2]; A.w = p[9];
            Bxy.x = p[3]; Bxy.y = p[4]; Bz = p[5];
        }
        ldsA[r] = A;
        ldsB01[r] = Bxy;
        ldsB2[r] = Bz;
    }
    __syncthreads();

    // ---- per-pixel-pair center state, packed over p ----
    const int gx = bx0 + lx;
    const int row0 = (ty * PY + HALO) * RX + HALO + lx;
    const float4 A0 = ldsA[row0];
    const float4 A1 = ldsA[row0 + RX];
    const float2 B0 = ldsB01[row0];
    const float2 B1 = ldsB01[row0 + RX];
    const float  B0z = ldsB2[row0];
    const float  B1z = ldsB2[row0 + RX];
    const f2 cnx2 = {B0.x, B1.x};
    const f2 cny2 = {B0.y, B1.y};
    const f2 cnz2 = {B0z, B1z};
    const f2 cz2  = {A0.w, A1.w};
    f2 rdz2;
#pragma unroll
    for (int p = 0; p < PY; ++p) {
        const int gy = by0 + ty * PY + p;
        float dzv = 0.f;
        if (gy < IMG_H) dzv = in[(gy * IMG_W + gx) * CHN + 10];
        // dz<=0 -> rcp(0)=+inf -> rrc=-inf -> clamped to C/EPS, matching
        // 1/max(dz*dist, EPS).
        const float rv = __builtin_amdgcn_rcpf(fmaxf(dzv, 0.f));
        if (p == 0) rdz2.x = rv; else rdz2.y = rv;
    }

    const float RCLAMP = -14426.9504f;   // C_DEPTH * 1e4 (== C/EPS)

    // ---- depth-slope hoist: r2d[k] = max(IC[k]*rdz, RCLAMP), per pixel ----
    f2 r2d[NS];
#pragma unroll
    for (int k = 0; k < NS; ++k) {
        const f2 rrc = (f2)(IC.v[k]) * rdz2;
        r2d[k].x = fmaxf(rrc.x, RCLAMP);
        r2d[k].y = fmaxf(rrc.y, RCLAMP);
    }

    f2 accx2 = (f2)(0.f), accy2 = (f2)(0.f), accz2 = (f2)(0.f), accw2 = (f2)(0.f);

    // j = dy + p; FULL unroll: j, dx, slots, lw all compile-time.
#pragma unroll
    for (int j = -HALO; j <= HALO + 1; ++j) {
        const int dy0 = j, dy1 = j - 1;
        const int m0 = R2MAX - dy0 * dy0;
        const int m1 = R2MAX - dy1 * dy1;
        const int m2 = m0 > m1 ? m0 : m1;
        const int rowb = (ty * PY + HALO + j) * RX + HALO + lx;
#pragma unroll
        for (int dxi = 0; dxi < 13; ++dxi) {
            const int dx = dxi - 6;
            if (dx * dx <= m2) {                    // compile-time guard
                const int   s0  = slotOf(dy0, dx);  // compile-time slots
                const int   s1  = slotOf(dy1, dx);
                const float lw0 = lwOf(dy0, dx);
                const float lw1 = lwOf(dy1, dx);
                const float4 A   = ldsA[rowb + dx];
                const float2 Bxy = ldsB01[rowb + dx];
                const float  Bz  = ldsB2[rowb + dx];
                // packed over p:
                const f2 dz2  = (f2)(A.w) - cz2;                       // pk_add
                const f2 dot2 = (f2)(Bxy.x) * cnx2 + ((f2)(Bxy.y) * cny2 + (f2)(Bz) * cnz2);
                f2 c2;
                c2.x = fminf(fmaxf(dot2.x, 0.f), 1.f);                 // med3
                c2.y = fminf(fmaxf(dot2.y, 0.f), 1.f);
                f2 s = c2 * c2;                                        // ^128 by
                s = s * s; s = s * s; s = s * s;                       // 7 pk_mul
                s = s * s; s = s * s; s = s * s;
                f2 arg;                                                // |dz|: VOP3 abs mod;
                arg.x = fmaf(fabsf(dz2.x), r2d[s0].x, lw0);            // r2d: hoisted slope
                arg.y = fmaf(fabsf(dz2.y), r2d[s1].y, lw1);
                f2 w2;
                w2.x = __builtin_amdgcn_exp2f(arg.x);
                w2.y = __builtin_amdgcn_exp2f(arg.y);
                w2 *= s;                                               // pk_mul
                accx2 = (f2)(A.x) * w2 + accx2;                        // 4x pk_fma
                accy2 = (f2)(A.y) * w2 + accy2;
                accz2 = (f2)(A.z) * w2 + accz2;
                accw2 += w2;
            }
        }
    }

    // ---- epilogue: out = accum_col / max(accum_w, EPS) ----
#pragma unroll
    for (int p = 0; p < PY; ++p) {
        const int gy = by0 + ty * PY + p;
        if (gy < IMG_H) {
            const float aw = (p == 0) ? accw2.x : accw2.y;
            const float inv = __builtin_amdgcn_rcpf(fmaxf(aw, 1e-4f));
            const int o = (gy * IMG_W + gx) * 3;
            out[o + 0] = ((p == 0) ? accx2.x : accx2.y) * inv;
            out[o + 1] = ((p == 0) ? accy2.x : accy2.y) * inv;
            out[o + 2] = ((p == 0) ? accz2.x : accz2.y) * inv;
        }
    }
}

extern "C" void kernel_launch(void* const* d_in, const int* in_sizes, int n_in,
                              void* d_out, int out_size, void* d_ws, size_t ws_size,
                              hipStream_t stream) {
    const float* in = (const float*)d_in[0];
    float* out = (float*)d_out;
    dim3 grid(IMG_W / TLX, (IMG_H + TLY - 1) / TLY);   // 60 x 68
    dim3 block(32, 8);                                 // 256 thr = 4 waves
    hipLaunchKernelGGL(bilateral_denoise_kernel, grid, block, 0, stream, in, out);
}

// Round 7
// 207.886 us; speedup vs baseline: 1.0506x; 1.0506x over previous
//
#include <hip/hip_runtime.h>

// Bilateral denoiser, 1080x1920x11 fp32 -> 1080x1920x3 fp32.
// d^2 <= 36 taps (113). Two y-adjacent pixels per thread packed into
// v_pk_*_f32 lanes (f2).
//
// R7: depth-slope hoist, register-guaranteed. R6's local f2 r2d[19] went
// to SCRATCH (VGPR stayed 52; VALUBusy 78->58; dur 124->176): SROA runs
// before loop-unroll, so backend-constant indices were too late to
// promote the alloca. Fix: recursive templates Row<J>/Tap<J,DXI> make
// j/dx/slot FRONT-END constants -> r2d[s] is a constant GEP at
// instantiation -> SROA promotes to 38 VGPRs.
// Math bit-identical to R2 (measured best, 124 us):
//   w = exp2( |dz|*max(invdC*rdz, C*1e4) + lw + 128*log2(clamp(dot,0,1)) )
// with max(invdC*rdz, RCLAMP) hoisted per distinct d^2 (19 slots,
// saves rrc pk_mul + 2 fmax = 8 issue-cy/tap and shortens the chain).
// Geometry: R2 tile 32x16, 256 thr, slim LDS 34496 B -> 4 blocks/CU.

namespace {
constexpr int IMG_H = 1080;
constexpr int IMG_W = 1920;
constexpr int CHN   = 11;
constexpr int TLX   = 32;
constexpr int TLY   = 16;
constexpr int HALO  = 6;
constexpr int RX    = TLX + 2 * HALO;   // 44
constexpr int RY    = TLY + 2 * HALO;   // 28
constexpr int PY    = 2;
constexpr int R2MAX = 36;

constexpr double CD = -1.4426950408889634;   // -log2(e)

// distinct d^2 values <= 36 (a^2+b^2, a,b in 0..6)
constexpr int NS = 19;
constexpr int D2V[NS] = {0,1,2,4,5,8,9,10,13,16,17,18,20,25,26,29,32,34,36};

constexpr float icOf(int d2) {
    if (d2 == 0) return -1e30f;          // center: forces r2 -> RCLAMP; lw=0
    double s = (double)d2, x = s;
    for (int it = 0; it < 60; ++it) x = 0.5 * (x + s / x);
    return (float)(CD / x);              // -log2e / dist
}
struct ICTab {
    float v[NS];
    constexpr ICTab() : v{} { for (int k = 0; k < NS; ++k) v[k] = icOf(D2V[k]); }
};
constexpr ICTab IC{};

constexpr int slotOf(int dy, int dx) {
    const int d2 = dy * dy + dx * dx;
    for (int k = 0; k < NS; ++k) if (D2V[k] == d2) return k;
    return 1;                            // inactive half (d2>36): any finite slot
}
constexpr float lwOf(int dy, int dx) {
    const int d2 = dy * dy + dx * dx;
    if (d2 == 0) return 0.f;
    if (d2 <= R2MAX) return (float)(0.5 * CD * d2);  // -log2e/2 * d^2
    return -1e30f;                       // pruned/out-of-window: w -> 0
}
}

typedef float f2 __attribute__((ext_vector_type(2)));

struct Ctx {
    const float4* __restrict__ A;        // LDS {col0,col1,col2,z}
    const float2* __restrict__ B01;      // LDS {nrm0,nrm1}
    const float*  __restrict__ B2;       // LDS nrm2
    int base;                            // center LDS index
    f2 cnx2, cny2, cnz2, cz2;
    f2 r2d[NS];                          // hoisted depth slopes (template-const idx only)
    f2 accx, accy, accz, accw;
};

template<int J, int DXI>
struct Tap {
    static __device__ __forceinline__ void run(Ctx& c, int rowb) {
        constexpr int dx  = DXI - 6;
        constexpr int dy0 = J, dy1 = J - 1;
        constexpr int m0 = R2MAX - dy0 * dy0;
        constexpr int m1 = R2MAX - dy1 * dy1;
        constexpr int m2 = (m0 > m1) ? m0 : m1;
        if constexpr (dx * dx <= m2) {
            constexpr int   s0  = slotOf(dy0, dx);   // front-end constants
            constexpr int   s1  = slotOf(dy1, dx);
            constexpr float lw0 = lwOf(dy0, dx);
            constexpr float lw1 = lwOf(dy1, dx);
            const int idx = rowb + dx;
            const float4 Av  = c.A[idx];
            const float2 Bxy = c.B01[idx];
            const float  Bz  = c.B2[idx];
            // packed over p:
            const f2 dz2  = (f2)(Av.w) - c.cz2;                        // pk_add
            const f2 dot2 = (f2)(Bxy.x) * c.cnx2 +
                            ((f2)(Bxy.y) * c.cny2 + (f2)(Bz) * c.cnz2);
            f2 cv;
            cv.x = fminf(fmaxf(dot2.x, 0.f), 1.f);                     // med3
            cv.y = fminf(fmaxf(dot2.y, 0.f), 1.f);
            f2 lc;                                                     // log2(c): trans
            lc.x = __builtin_amdgcn_logf(cv.x);                        // log2(0)=-inf -> w=0
            lc.y = __builtin_amdgcn_logf(cv.y);
            f2 arg;                                                    // |dz|: VOP3 abs mod
            arg.x = fmaf(fabsf(dz2.x), c.r2d[s0].x, lw0);              // hoisted slope
            arg.y = fmaf(fabsf(dz2.y), c.r2d[s1].y, lw1);
            const f2 argt = lc * 128.f + arg;                          // pk_fma
            f2 w2;
            w2.x = __builtin_amdgcn_exp2f(argt.x);
            w2.y = __builtin_amdgcn_exp2f(argt.y);
            c.accx = (f2)(Av.x) * w2 + c.accx;                         // 4x pk_fma
            c.accy = (f2)(Av.y) * w2 + c.accy;
            c.accz = (f2)(Av.z) * w2 + c.accz;
            c.accw += w2;
        }
        if constexpr (DXI + 1 < 13) Tap<J, DXI + 1>::run(c, rowb);
    }
};

template<int J>
struct Row {
    static __device__ __forceinline__ void run(Ctx& c) {
        Tap<J, 0>::run(c, c.base + J * RX);
        if constexpr (J < HALO + 1) Row<J + 1>::run(c);
    }
};

__global__ __launch_bounds__(256, 4)
void bilateral_denoise_kernel(const float* __restrict__ in, float* __restrict__ out) {
    __shared__ float4 ldsA[RY * RX];    // {col0, col1, col2, z}   19712 B
    __shared__ float2 ldsB01[RY * RX];  // {nrm0, nrm1}             9856 B
    __shared__ float  ldsB2[RY * RX];   // nrm2                     4928 B
                                        // total 34496 B -> 4 blocks/CU

    const int lx  = threadIdx.x;
    const int ty  = threadIdx.y;
    const int bx0 = blockIdx.x * TLX;
    const int by0 = blockIdx.y * TLY;
    const int tid = ty * 32 + lx;

    // ---- stage tile + halo (OOB -> zeros; nrm=0 => dot=0 => log=-inf => w=0) ----
    for (int r = tid; r < RY * RX; r += 256) {
        const int ry = r / RX;
        const int rx = r - ry * RX;
        const int gy = by0 - HALO + ry;
        const int gx = bx0 - HALO + rx;
        float4 A = make_float4(0.f, 0.f, 0.f, 0.f);
        float2 Bxy = make_float2(0.f, 0.f);
        float  Bz = 0.f;
        if ((unsigned)gy < (unsigned)IMG_H && (unsigned)gx < (unsigned)IMG_W) {
            const float* p = in + (gy * IMG_W + gx) * CHN;
            A.x = p[0]; A.y = p[1]; A.z = p[2]; A.w = p[9];
            Bxy.x = p[3]; Bxy.y = p[4]; Bz = p[5];
        }
        ldsA[r] = A;
        ldsB01[r] = Bxy;
        ldsB2[r] = Bz;
    }
    __syncthreads();

    // ---- per-pixel-pair center state, packed over p ----
    const int gx = bx0 + lx;
    const int row0 = (ty * PY + HALO) * RX + HALO + lx;
    const float4 A0 = ldsA[row0];
    const float4 A1 = ldsA[row0 + RX];
    const float2 B0 = ldsB01[row0];
    const float2 B1 = ldsB01[row0 + RX];
    const float  B0z = ldsB2[row0];
    const float  B1z = ldsB2[row0 + RX];

    Ctx c;
    c.A = ldsA; c.B01 = ldsB01; c.B2 = ldsB2;
    c.base = row0;
    c.cnx2 = {B0.x, B1.x};
    c.cny2 = {B0.y, B1.y};
    c.cnz2 = {B0z, B1z};
    c.cz2  = {A0.w, A1.w};

    f2 rdz2;
#pragma unroll
    for (int p = 0; p < PY; ++p) {
        const int gy = by0 + ty * PY + p;
        float dzv = 0.f;
        if (gy < IMG_H) dzv = in[(gy * IMG_W + gx) * CHN + 10];
        // dz<=0 -> rcp(0)=+inf -> rrc=-inf -> clamped to C/EPS, matching
        // 1/max(dz*dist, EPS).
        const float rv = __builtin_amdgcn_rcpf(fmaxf(dzv, 0.f));
        if (p == 0) rdz2.x = rv; else rdz2.y = rv;
    }

    const float RCLAMP = -14426.9504f;   // C_DEPTH * 1e4 (== C/EPS)

    // ---- depth-slope hoist: r2d[k] = max(IC[k]*rdz, RCLAMP), per pixel ----
#pragma unroll
    for (int k = 0; k < NS; ++k) {
        const f2 rrc = (f2)(IC.v[k]) * rdz2;
        c.r2d[k].x = fmaxf(rrc.x, RCLAMP);
        c.r2d[k].y = fmaxf(rrc.y, RCLAMP);
    }

    c.accx = (f2)(0.f); c.accy = (f2)(0.f); c.accz = (f2)(0.f); c.accw = (f2)(0.f);

    Row<-HALO>::run(c);                  // fully compile-time tap sweep

    // ---- epilogue: out = accum_col / max(accum_w, EPS) ----
#pragma unroll
    for (int p = 0; p < PY; ++p) {
        const int gy = by0 + ty * PY + p;
        if (gy < IMG_H) {
            const float aw = (p == 0) ? c.accw.x : c.accw.y;
            const float inv = __builtin_amdgcn_rcpf(fmaxf(aw, 1e-4f));
            const int o = (gy * IMG_W + gx) * 3;
            out[o + 0] = ((p == 0) ? c.accx.x : c.accx.y) * inv;
            out[o + 1] = ((p == 0) ? c.accy.x : c.accy.y) * inv;
            out[o + 2] = ((p == 0) ? c.accz.x : c.accz.y) * inv;
        }
    }
}

extern "C" void kernel_launch(void* const* d_in, const int* in_sizes, int n_in,
                              void* d_out, int out_size, void* d_ws, size_t ws_size,
                              hipStream_t stream) {
    const float* in = (const float*)d_in[0];
    float* out = (float*)d_out;
    dim3 grid(IMG_W / TLX, (IMG_H + TLY - 1) / TLY);   // 60 x 68
    dim3 block(32, 8);                                 // 256 thr = 4 waves
    hipLaunchKernelGGL(bilateral_denoise_kernel, grid, block, 0, stream, in, out);
}

// Round 8
// 206.669 us; speedup vs baseline: 1.0568x; 1.0059x over previous
//
#include <hip/hip_runtime.h>

// Bilateral denoiser, 1080x1920x11 fp32 -> 1080x1920x3 fp32.
// d^2 <= 36 taps (113). Two y-adjacent pixels per thread packed into
// v_pk_*_f32 lanes (f2).
//
// R8: depth-slope hoist, REMAT-PROOF. R7's template-const indices avoided
// scratch but the compiler rematerialized fmax(ic*rdz,RCLAMP) into every
// tap instead of carrying 38 regs (VGPR stayed 56; dur == R2's 123.6).
// Fix: pin each hoisted value with empty asm volatile("":"+v"(x)) after
// computing it -- the asm "redefines" the value, severing the def-use
// chain remat needs; taps must consume the carried register.
// Saves rrc pk_mul + 2 fmax = 8 of ~92 issue-cy/tap and shortens the
// rdz->clamp->fma->exp chain. 56+38=94 VGPR < 128 cap (256thr x 4/EU).
// Math bit-identical to R2 (measured 123.6 us):
//   w = exp2( |dz|*max(invdC*rdz, C*1e4) + lw + 128*log2(clamp(dot,0,1)) )
// Geometry: tile 32x16, 256 thr, slim LDS 34496 B -> 4 blocks/CU.

namespace {
constexpr int IMG_H = 1080;
constexpr int IMG_W = 1920;
constexpr int CHN   = 11;
constexpr int TLX   = 32;
constexpr int TLY   = 16;
constexpr int HALO  = 6;
constexpr int RX    = TLX + 2 * HALO;   // 44
constexpr int RY    = TLY + 2 * HALO;   // 28
constexpr int PY    = 2;
constexpr int R2MAX = 36;

constexpr double CD = -1.4426950408889634;   // -log2(e)

// distinct d^2 values <= 36 (a^2+b^2, a,b in 0..6)
constexpr int NS = 19;
constexpr int D2V[NS] = {0,1,2,4,5,8,9,10,13,16,17,18,20,25,26,29,32,34,36};

constexpr float icOf(int d2) {
    if (d2 == 0) return -1e30f;          // center: forces r2 -> RCLAMP; lw=0
    double s = (double)d2, x = s;
    for (int it = 0; it < 60; ++it) x = 0.5 * (x + s / x);
    return (float)(CD / x);              // -log2e / dist
}
struct ICTab {
    float v[NS];
    constexpr ICTab() : v{} { for (int k = 0; k < NS; ++k) v[k] = icOf(D2V[k]); }
};
constexpr ICTab IC{};

constexpr int slotOf(int dy, int dx) {
    const int d2 = dy * dy + dx * dx;
    for (int k = 0; k < NS; ++k) if (D2V[k] == d2) return k;
    return 1;                            // inactive half (d2>36): any finite slot
}
constexpr float lwOf(int dy, int dx) {
    const int d2 = dy * dy + dx * dx;
    if (d2 == 0) return 0.f;
    if (d2 <= R2MAX) return (float)(0.5 * CD * d2);  // -log2e/2 * d^2
    return -1e30f;                       // pruned/out-of-window: w -> 0
}
}

typedef float f2 __attribute__((ext_vector_type(2)));

struct Ctx {
    const float4* __restrict__ A;        // LDS {col0,col1,col2,z}
    const float2* __restrict__ B01;      // LDS {nrm0,nrm1}
    const float*  __restrict__ B2;       // LDS nrm2
    int base;                            // center LDS index
    f2 cnx2, cny2, cnz2, cz2;
    float r2x[NS], r2y[NS];              // hoisted depth slopes (asm-pinned regs)
    f2 accx, accy, accz, accw;
};

template<int J, int DXI>
struct Tap {
    static __device__ __forceinline__ void run(Ctx& c, int rowb) {
        constexpr int dx  = DXI - 6;
        constexpr int dy0 = J, dy1 = J - 1;
        constexpr int m0 = R2MAX - dy0 * dy0;
        constexpr int m1 = R2MAX - dy1 * dy1;
        constexpr int m2 = (m0 > m1) ? m0 : m1;
        if constexpr (dx * dx <= m2) {
            constexpr int   s0  = slotOf(dy0, dx);   // front-end constants
            constexpr int   s1  = slotOf(dy1, dx);
            constexpr float lw0 = lwOf(dy0, dx);
            constexpr float lw1 = lwOf(dy1, dx);
            const int idx = rowb + dx;
            const float4 Av  = c.A[idx];
            const float2 Bxy = c.B01[idx];
            const float  Bz  = c.B2[idx];
            // packed over p:
            const f2 dz2  = (f2)(Av.w) - c.cz2;                        // pk_add
            const f2 dot2 = (f2)(Bxy.x) * c.cnx2 +
                            ((f2)(Bxy.y) * c.cny2 + (f2)(Bz) * c.cnz2);
            f2 cv;
            cv.x = fminf(fmaxf(dot2.x, 0.f), 1.f);                     // med3
            cv.y = fminf(fmaxf(dot2.y, 0.f), 1.f);
            f2 lc;                                                     // log2(c): trans
            lc.x = __builtin_amdgcn_logf(cv.x);                        // log2(0)=-inf -> w=0
            lc.y = __builtin_amdgcn_logf(cv.y);
            f2 arg;                                                    // |dz|: VOP3 abs mod
            arg.x = fmaf(fabsf(dz2.x), c.r2x[s0], lw0);                // hoisted slope
            arg.y = fmaf(fabsf(dz2.y), c.r2y[s1], lw1);
            const f2 argt = lc * 128.f + arg;                          // pk_fma
            f2 w2;
            w2.x = __builtin_amdgcn_exp2f(argt.x);
            w2.y = __builtin_amdgcn_exp2f(argt.y);
            c.accx = (f2)(Av.x) * w2 + c.accx;                         // 4x pk_fma
            c.accy = (f2)(Av.y) * w2 + c.accy;
            c.accz = (f2)(Av.z) * w2 + c.accz;
            c.accw += w2;
        }
        if constexpr (DXI + 1 < 13) Tap<J, DXI + 1>::run(c, rowb);
    }
};

template<int J>
struct Row {
    static __device__ __forceinline__ void run(Ctx& c) {
        Tap<J, 0>::run(c, c.base + J * RX);
        if constexpr (J < HALO + 1) Row<J + 1>::run(c);
    }
};

__global__ __launch_bounds__(256, 4)
void bilateral_denoise_kernel(const float* __restrict__ in, float* __restrict__ out) {
    __shared__ float4 ldsA[RY * RX];    // {col0, col1, col2, z}   19712 B
    __shared__ float2 ldsB01[RY * RX];  // {nrm0, nrm1}             9856 B
    __shared__ float  ldsB2[RY * RX];   // nrm2                     4928 B
                                        // total 34496 B -> 4 blocks/CU

    const int lx  = threadIdx.x;
    const int ty  = threadIdx.y;
    const int bx0 = blockIdx.x * TLX;
    const int by0 = blockIdx.y * TLY;
    const int tid = ty * 32 + lx;

    // ---- stage tile + halo (OOB -> zeros; nrm=0 => dot=0 => log=-inf => w=0) ----
    for (int r = tid; r < RY * RX; r += 256) {
        const int ry = r / RX;
        const int rx = r - ry * RX;
        const int gy = by0 - HALO + ry;
        const int gx = bx0 - HALO + rx;
        float4 A = make_float4(0.f, 0.f, 0.f, 0.f);
        float2 Bxy = make_float2(0.f, 0.f);
        float  Bz = 0.f;
        if ((unsigned)gy < (unsigned)IMG_H && (unsigned)gx < (unsigned)IMG_W) {
            const float* p = in + (gy * IMG_W + gx) * CHN;
            A.x = p[0]; A.y = p[1]; A.z = p[2]; A.w = p[9];
            Bxy.x = p[3]; Bxy.y = p[4]; Bz = p[5];
        }
        ldsA[r] = A;
        ldsB01[r] = Bxy;
        ldsB2[r] = Bz;
    }
    __syncthreads();

    // ---- per-pixel-pair center state, packed over p ----
    const int gx = bx0 + lx;
    const int row0 = (ty * PY + HALO) * RX + HALO + lx;
    const float4 A0 = ldsA[row0];
    const float4 A1 = ldsA[row0 + RX];
    const float2 B0 = ldsB01[row0];
    const float2 B1 = ldsB01[row0 + RX];
    const float  B0z = ldsB2[row0];
    const float  B1z = ldsB2[row0 + RX];

    Ctx c;
    c.A = ldsA; c.B01 = ldsB01; c.B2 = ldsB2;
    c.base = row0;
    c.cnx2 = {B0.x, B1.x};
    c.cny2 = {B0.y, B1.y};
    c.cnz2 = {B0z, B1z};
    c.cz2  = {A0.w, A1.w};

    f2 rdz2;
#pragma unroll
    for (int p = 0; p < PY; ++p) {
        const int gy = by0 + ty * PY + p;
        float dzv = 0.f;
        if (gy < IMG_H) dzv = in[(gy * IMG_W + gx) * CHN + 10];
        // dz<=0 -> rcp(0)=+inf -> rrc=-inf -> clamped to C/EPS, matching
        // 1/max(dz*dist, EPS).
        const float rv = __builtin_amdgcn_rcpf(fmaxf(dzv, 0.f));
        if (p == 0) rdz2.x = rv; else rdz2.y = rv;
    }

    const float RCLAMP = -14426.9504f;   // C_DEPTH * 1e4 (== C/EPS)

    // ---- depth-slope hoist: r2{x,y}[k] = max(IC[k]*rdz, RCLAMP) ----
    // asm pin "redefines" each value: rematerialization into the taps is
    // impossible; the 38 values stay resident in VGPRs (94 < 128 cap).
#pragma unroll
    for (int k = 0; k < NS; ++k) {
        float vx = fmaxf(IC.v[k] * rdz2.x, RCLAMP);
        float vy = fmaxf(IC.v[k] * rdz2.y, RCLAMP);
        asm volatile("" : "+v"(vx), "+v"(vy));
        c.r2x[k] = vx;
        c.r2y[k] = vy;
    }

    c.accx = (f2)(0.f); c.accy = (f2)(0.f); c.accz = (f2)(0.f); c.accw = (f2)(0.f);

    Row<-HALO>::run(c);                  // fully compile-time tap sweep

    // ---- epilogue: out = accum_col / max(accum_w, EPS) ----
#pragma unroll
    for (int p = 0; p < PY; ++p) {
        const int gy = by0 + ty * PY + p;
        if (gy < IMG_H) {
            const float aw = (p == 0) ? c.accw.x : c.accw.y;
            const float inv = __builtin_amdgcn_rcpf(fmaxf(aw, 1e-4f));
            const int o = (gy * IMG_W + gx) * 3;
            out[o + 0] = ((p == 0) ? c.accx.x : c.accx.y) * inv;
            out[o + 1] = ((p == 0) ? c.accy.x : c.accy.y) * inv;
            out[o + 2] = ((p == 0) ? c.accz.x : c.accz.y) * inv;
        }
    }
}

extern "C" void kernel_launch(void* const* d_in, const int* in_sizes, int n_in,
                              void* d_out, int out_size, void* d_ws, size_t ws_size,
                              hipStream_t stream) {
    const float* in = (const float*)d_in[0];
    float* out = (float*)d_out;
    dim3 grid(IMG_W / TLX, (IMG_H + TLY - 1) / TLY);   // 60 x 68
    dim3 block(32, 8);                                 // 256 thr = 4 waves
    hipLaunchKernelGGL(bilateral_denoise_kernel, grid, block, 0, stream, in, out);
}